// Round 1
// baseline (288.364 us; speedup 1.0000x reference)
//
#include <hip/hip_runtime.h>
#include <math.h>

#define BATCH_N 16384

// ---------------------------------------------------------------------------
// K1: conv1 (1->6, 5x5, VALID) + bias + relu + maxpool 2x2
//     x: (B,1,28,28) -> out: (B,6,12,12)
// One block per sample, 256 threads. Input + weights staged in LDS.
// Each pooled output reads a 6x6 patch into registers; the 4 conv positions
// of the pool window share the patch (100 MACs per 25-ish LDS reads).
// ---------------------------------------------------------------------------
__global__ __launch_bounds__(256) void k1_conv1(const float* __restrict__ x,
                                                const float* __restrict__ w,
                                                const float* __restrict__ bias,
                                                float* __restrict__ out) {
    __shared__ float xs[784];
    __shared__ float ws[6 * 28];  // per-oc stride 28 (16B aligned chunks)
    const int b = blockIdx.x, tid = threadIdx.x;
    if (tid < 196) ((float4*)xs)[tid] = ((const float4*)(x + (size_t)b * 784))[tid];
    if (tid < 150) ws[(tid / 25) * 28 + tid % 25] = w[tid];
    __syncthreads();

    for (int idx = tid; idx < 864; idx += 256) {
        const int oc = idx / 144;
        const int r  = idx - oc * 144;
        const int py = r / 12, px = r - (r / 12) * 12;
        const float bv = bias[oc];
        float a00 = bv, a01 = bv, a10 = bv, a11 = bv;
        const float* wp = ws + oc * 28;
        const float* xp = xs + (2 * py) * 28 + 2 * px;
        float p[6][6];
#pragma unroll
        for (int rr = 0; rr < 6; rr++) {
            float2 u = *(const float2*)(xp + rr * 28);
            float2 v = *(const float2*)(xp + rr * 28 + 2);
            float2 t = *(const float2*)(xp + rr * 28 + 4);
            p[rr][0] = u.x; p[rr][1] = u.y; p[rr][2] = v.x;
            p[rr][3] = v.y; p[rr][4] = t.x; p[rr][5] = t.y;
        }
#pragma unroll
        for (int ky = 0; ky < 5; ky++)
#pragma unroll
            for (int kx = 0; kx < 5; kx++) {
                const float wv = wp[ky * 5 + kx];
                a00 = fmaf(wv, p[ky][kx],         a00);
                a01 = fmaf(wv, p[ky][kx + 1],     a01);
                a10 = fmaf(wv, p[ky + 1][kx],     a10);
                a11 = fmaf(wv, p[ky + 1][kx + 1], a11);
            }
        const float m = fmaxf(fmaxf(a00, a01), fmaxf(a10, a11));
        out[(size_t)b * 864 + idx] = fmaxf(m, 0.f);
    }
}

// ---------------------------------------------------------------------------
// K2: conv2 (6->16, 5x5, VALID) + bias + relu + maxpool 2x2
//     h1: (B,6,12,12) -> out: (B,256) flattened as (16,4,4)
// One block per sample, 256 threads = 16 oc x (4x4) pooled outputs.
// ---------------------------------------------------------------------------
__global__ __launch_bounds__(256) void k2_conv2(const float* __restrict__ h1,
                                                const float* __restrict__ w,
                                                const float* __restrict__ bias,
                                                float* __restrict__ out) {
    __shared__ float hs[864];
    __shared__ float ws[96 * 28];  // (oc*6+ic) stride 28
    const int b = blockIdx.x, tid = threadIdx.x;
    if (tid < 216) ((float4*)hs)[tid] = ((const float4*)(h1 + (size_t)b * 864))[tid];
    for (int i = tid; i < 2400; i += 256) ws[(i / 25) * 28 + i % 25] = w[i];
    __syncthreads();

    const int oc = tid >> 4, sp = tid & 15, py = sp >> 2, px = sp & 3;
    const float bv = bias[oc];
    float a00 = bv, a01 = bv, a10 = bv, a11 = bv;
    for (int ic = 0; ic < 6; ic++) {
        const float* xp = hs + ic * 144 + (2 * py) * 12 + 2 * px;
        float p[6][6];
#pragma unroll
        for (int rr = 0; rr < 6; rr++) {
            float2 u = *(const float2*)(xp + rr * 12);
            float2 v = *(const float2*)(xp + rr * 12 + 2);
            float2 t = *(const float2*)(xp + rr * 12 + 4);
            p[rr][0] = u.x; p[rr][1] = u.y; p[rr][2] = v.x;
            p[rr][3] = v.y; p[rr][4] = t.x; p[rr][5] = t.y;
        }
        const float* wp = ws + (oc * 6 + ic) * 28;
#pragma unroll
        for (int ky = 0; ky < 5; ky++)
#pragma unroll
            for (int kx = 0; kx < 5; kx++) {
                const float wv = wp[ky * 5 + kx];
                a00 = fmaf(wv, p[ky][kx],         a00);
                a01 = fmaf(wv, p[ky][kx + 1],     a01);
                a10 = fmaf(wv, p[ky + 1][kx],     a10);
                a11 = fmaf(wv, p[ky + 1][kx + 1], a11);
            }
    }
    const float m = fmaxf(fmaxf(a00, a01), fmaxf(a10, a11));
    out[(size_t)b * 256 + tid] = fmaxf(m, 0.f);
}

// ---------------------------------------------------------------------------
// K3: fc1 (256->120) + bias + relu, then fc2 (120->4) + bias + pi*sigmoid
//     h2: (B,256) -> angles: (B,4)
// Block = 64 samples x 128 outs (120 used). 256 threads as 16x16, each thread
// a 4x8 register micro-tile. fc1 result round-trips through LDS for fc2.
// ---------------------------------------------------------------------------
__global__ __launch_bounds__(256) void k3_fc(const float* __restrict__ h2,
                                             const float* __restrict__ w1,
                                             const float* __restrict__ b1,
                                             const float* __restrict__ w2,
                                             const float* __restrict__ b2,
                                             float* __restrict__ angles) {
    __shared__ float As[64 * 17];
    __shared__ float Bs[128 * 17];
    __shared__ float Hs[64 * 121];
    const int tid = threadIdx.x;
    const int s0 = blockIdx.x * 64;
    const int tx = tid & 15, ty = tid >> 4;

    float acc[4][8];
#pragma unroll
    for (int i = 0; i < 4; i++)
#pragma unroll
        for (int j = 0; j < 8; j++) acc[i][j] = 0.f;

    for (int k0 = 0; k0 < 256; k0 += 16) {
#pragma unroll
        for (int i = 0; i < 4; i++)
            As[(ty + 16 * i) * 17 + tx] = h2[(size_t)(s0 + ty + 16 * i) * 256 + k0 + tx];
#pragma unroll
        for (int j = 0; j < 8; j++) {
            const int n = ty + 16 * j;  // 0..127
            Bs[n * 17 + tx] = (n < 120) ? w1[(size_t)n * 256 + k0 + tx] : 0.f;
        }
        __syncthreads();
#pragma unroll
        for (int kk = 0; kk < 16; kk++) {
            float av[4], bv[8];
#pragma unroll
            for (int i = 0; i < 4; i++) av[i] = As[(ty + 16 * i) * 17 + kk];
#pragma unroll
            for (int j = 0; j < 8; j++) bv[j] = Bs[(tx + 16 * j) * 17 + kk];
#pragma unroll
            for (int i = 0; i < 4; i++)
#pragma unroll
                for (int j = 0; j < 8; j++) acc[i][j] = fmaf(av[i], bv[j], acc[i][j]);
        }
        __syncthreads();
    }

    // bias + relu -> Hs
#pragma unroll
    for (int j = 0; j < 8; j++) {
        const int n = tx + 16 * j;
        if (n < 120) {
            const float bv = b1[n];
#pragma unroll
            for (int i = 0; i < 4; i++)
                Hs[(ty + 16 * i) * 121 + n] = fmaxf(acc[i][j] + bv, 0.f);
        }
    }
    __syncthreads();

    // fc2 + sigmoid: 64 samples x 4 feats = 256 tasks
    const int s = tid >> 2, m = tid & 3;
    float f = b2[m];
    for (int n = 0; n < 120; n++) f = fmaf(w2[m * 120 + n], Hs[s * 121 + n], f);
    const float ang = 3.14159265358979323846f / (1.f + expf(-f));
    angles[(size_t)(s0 + s) * 4 + m] = ang;
}

// ---------------------------------------------------------------------------
// K4: 4-qubit, 3-layer data-reuploading circuit + classifier (4->10)
// One thread per sample; 16 complex amplitudes fully unrolled in registers.
// Qubit w <-> bit (3-w) of the flat index (q0 is MSB).
// ---------------------------------------------------------------------------
__global__ __launch_bounds__(256) void k4_circuit(const float* __restrict__ angles,
                                                  const float* __restrict__ qw,
                                                  const float* __restrict__ cw,
                                                  const float* __restrict__ cb,
                                                  float* __restrict__ out) {
    const int b = blockIdx.x * 256 + threadIdx.x;
    const float4 a4 = ((const float4*)angles)[b];
    const float av[4] = {a4.x, a4.y, a4.z, a4.w};

    float sr[16], si[16];
#pragma unroll
    for (int i = 0; i < 16; i++) { sr[i] = 0.f; si[i] = 0.f; }
    sr[0] = 1.f;

#pragma unroll
    for (int l = 0; l < 3; l++) {
        // Rot(phi, theta, omega) on each qubit (batch-uniform matrices)
#pragma unroll
        for (int w = 0; w < 4; w++) {
            const float phi = qw[(l * 4 + w) * 3 + 0];
            const float th  = qw[(l * 4 + w) * 3 + 1];
            const float om  = qw[(l * 4 + w) * 3 + 2];
            const float ct = cosf(0.5f * th), st = sinf(0.5f * th);
            const float ap = 0.5f * (phi + om), bm = 0.5f * (phi - om);
            const float ca = cosf(ap), sa = sinf(ap);
            const float cbm = cosf(bm), sbm = sinf(bm);
            const float m00r =  ct * ca,  m00i = -ct * sa;
            const float m01r = -st * cbm, m01i = -st * sbm;
            const float m10r =  st * cbm, m10i = -st * sbm;
            const float m11r =  ct * ca,  m11i =  ct * sa;
            const int mask = 8 >> w;
#pragma unroll
            for (int i = 0; i < 16; i++)
                if (!(i & mask)) {
                    const int j = i | mask;
                    const float xr = sr[i], xi = si[i], yr = sr[j], yi = si[j];
                    sr[i] = m00r * xr - m00i * xi + m01r * yr - m01i * yi;
                    si[i] = m00r * xi + m00i * xr + m01r * yi + m01i * yr;
                    sr[j] = m10r * xr - m10i * xi + m11r * yr - m11i * yi;
                    si[j] = m10r * xi + m10i * xr + m11r * yi + m11i * yr;
                }
        }
        // CNOT ring (0,1),(1,2),(2,3),(3,0)
#pragma unroll
        for (int w = 0; w < 4; w++) {
            const int mc = 8 >> w, mt = 8 >> ((w + 1) & 3);
#pragma unroll
            for (int i = 0; i < 16; i++)
                if ((i & mc) && !(i & mt)) {
                    const int j = i | mt;
                    const float tr = sr[i], ti = si[i];
                    sr[i] = sr[j]; si[i] = si[j];
                    sr[j] = tr;    si[j] = ti;
                }
        }
        // RX(angle_w) on each qubit (per-sample)
#pragma unroll
        for (int w = 0; w < 4; w++) {
            const float c = cosf(0.5f * av[w]), s = sinf(0.5f * av[w]);
            const int mask = 8 >> w;
#pragma unroll
            for (int i = 0; i < 16; i++)
                if (!(i & mask)) {
                    const int j = i | mask;
                    const float xr = sr[i], xi = si[i], yr = sr[j], yi = si[j];
                    sr[i] = c * xr + s * yi;
                    si[i] = c * xi - s * yr;
                    sr[j] = c * yr + s * xi;
                    si[j] = c * yi - s * xr;
                }
        }
    }

    // <Z_w> then classifier
    float z[4];
#pragma unroll
    for (int w = 0; w < 4; w++) {
        const int mask = 8 >> w;
        float acc = 0.f;
#pragma unroll
        for (int i = 0; i < 16; i++) {
            const float p = sr[i] * sr[i] + si[i] * si[i];
            acc += (i & mask) ? -p : p;
        }
        z[w] = acc;
    }
#pragma unroll
    for (int c = 0; c < 10; c++) {
        float v = cb[c];
#pragma unroll
        for (int w = 0; w < 4; w++) v = fmaf(cw[c * 4 + w], z[w], v);
        out[(size_t)b * 10 + c] = v;
    }
}

// ---------------------------------------------------------------------------
extern "C" void kernel_launch(void* const* d_in, const int* in_sizes, int n_in,
                              void* d_out, int out_size, void* d_ws, size_t ws_size,
                              hipStream_t stream) {
    const float* x   = (const float*)d_in[0];
    const float* c1w = (const float*)d_in[1];
    const float* c1b = (const float*)d_in[2];
    const float* c2w = (const float*)d_in[3];
    const float* c2b = (const float*)d_in[4];
    const float* f1w = (const float*)d_in[5];
    const float* f1b = (const float*)d_in[6];
    const float* f2w = (const float*)d_in[7];
    const float* f2b = (const float*)d_in[8];
    const float* qw  = (const float*)d_in[9];
    const float* cw  = (const float*)d_in[10];
    const float* cb  = (const float*)d_in[11];
    float* out = (float*)d_out;

    float* ws1 = (float*)d_ws;                        // B*864 fp32
    float* ws2 = ws1 + (size_t)BATCH_N * 864;         // B*256 fp32
    float* ws3 = ws2 + (size_t)BATCH_N * 256;         // B*4   fp32

    k1_conv1<<<BATCH_N, 256, 0, stream>>>(x, c1w, c1b, ws1);
    k2_conv2<<<BATCH_N, 256, 0, stream>>>(ws1, c2w, c2b, ws2);
    k3_fc<<<BATCH_N / 64, 256, 0, stream>>>(ws2, f1w, f1b, f2w, f2b, ws3);
    k4_circuit<<<BATCH_N / 256, 256, 0, stream>>>(ws3, qw, cw, cb, out);
}